// Round 6
// baseline (246.849 us; speedup 1.0000x reference)
//
#include <hip/hip_runtime.h>
#include <hip/hip_bf16.h>

#define U_    4096
#define I_    16384
#define D_    64
#define N_    20480     // U_ + I_
#define NEI   524288
#define NES   65536
#define CAPI  96        // interaction row-bucket capacity (mean 25.6; P(>=96) ~ 4e-25)
#define RCAPS 64        // social hash slots/row (mean nnz 16, max ~45)
#define L2CAP 1024      // g2-row unique-col capacity (mean ~250, max ~700; 1024 is ~11 sigma)

// ---------------- L1: workspace init + weight fold (independent work fused) ----------------
__global__ __launch_bounds__(256) void init_wab2_kernel(int* __restrict__ cnt, int* __restrict__ skey,
                                                        float* __restrict__ sval,
                                                        const float* __restrict__ Wa,
                                                        const float* __restrict__ Wb,
                                                        const float* __restrict__ w1,
                                                        float* __restrict__ Wa2, float* __restrict__ Wb2) {
    int b = blockIdx.x;
    if (b < 1024) {
        int tid = b * 256 + threadIdx.x;
        int stride = 1024 * 256;
        for (int o = tid; o < N_; o += stride) cnt[o] = 0;
        for (int o = tid; o < U_ * RCAPS; o += stride) { skey[o] = -1; sval[o] = 0.f; }
    } else {
        // fold: Wa2 = Wa @ w1[0:64,:], Wb2 = Wb @ w1[64:128,:]  (32 blocks)
        int o = (b - 1024) * 256 + threadIdx.x;   // 8192
        int mat = o >> 12;
        int i = (o >> 6) & 63;
        int j = o & 63;
        const float* M  = mat ? Wb : Wa;
        const float* W1 = w1 + mat * 64 * 64;
        float s = 0.f;
        #pragma unroll 8
        for (int k = 0; k < 64; ++k) s += M[i * 64 + k] * W1[k * 64 + j];
        (mat ? Wb2 : Wa2)[i * 64 + j] = s;
    }
}

// ---------------- L2: bucketed interaction edge build ----------------
__global__ void scatter_i_kernel(const int* __restrict__ rows, const int* __restrict__ cols,
                                 const float* __restrict__ vals,
                                 int* __restrict__ cnt, int2* __restrict__ ed) {
    int e = blockIdx.x * 256 + threadIdx.x;
    int r = rows[e];
    int pos = atomicAdd(&cnt[r], 1);
    if (pos < CAPI) ed[(size_t)r * CAPI + pos] = make_int2(cols[e], __float_as_int(vals[e]));
}

// ---------------- L3: spmm layer 1 + Pa/Pb projection (independent; fused) ----------------
__global__ __launch_bounds__(256) void spmm1_pab_kernel(const int* __restrict__ cnt, const int2* __restrict__ ed,
                                                        const float* __restrict__ ue, const float* __restrict__ ie,
                                                        float* __restrict__ h1,
                                                        const float* __restrict__ Wa2, const float* __restrict__ Wb2,
                                                        float* __restrict__ Pa, float* __restrict__ Pb) {
    int b = blockIdx.x;
    int wv = threadIdx.x >> 6, lane = threadIdx.x & 63;
    if (b < 5120) {
        int w = b * 4 + wv;          // 20480 rows
        int n = cnt[w]; if (n > CAPI) n = CAPI;
        const int2* row = ed + (size_t)w * CAPI;
        float acc = 0.f;
        #pragma unroll 4
        for (int j = 0; j < n; ++j) {
            int2 e = row[j];
            int c = e.x; float v = __int_as_float(e.y);
            const float* xp = (c < U_) ? (ue + (size_t)c * D_) : (ie + (size_t)(c - U_) * D_);
            acc += v * xp[lane];
        }
        h1[(size_t)w * D_ + lane] = acc;
    } else {
        int w = (b - 5120) * 4 + wv; // 4096 user rows
        float x = ue[w * 64 + lane];
        float accA = 0.f, accB = 0.f;
        #pragma unroll 8
        for (int k = 0; k < 64; ++k) {
            float xk = __shfl(x, k);
            accA += xk * Wa2[k * 64 + lane];   // same addr across waves -> L2 broadcast
            accB += xk * Wb2[k * 64 + lane];
        }
        Pa[w * 64 + lane] = accA;
        Pb[w * 64 + lane] = accB;
    }
}

// ---------------- L4: spmm layer 2 + edge MLP/hash-insert (independent; fused) ----------------
__global__ __launch_bounds__(256) void spmm2_edge_kernel(const int* __restrict__ cnt, const int2* __restrict__ ed,
                                                         const float* __restrict__ x, float* __restrict__ y,
                                                         const int* __restrict__ sr, const int* __restrict__ sc,
                                                         const float* __restrict__ Pa, const float* __restrict__ Pb,
                                                         const float* __restrict__ b1, const float* __restrict__ w2,
                                                         const float* __restrict__ b2,
                                                         int* __restrict__ skey, float* __restrict__ sval) {
    int b = blockIdx.x;
    if (b < 5120) {
        int wv = threadIdx.x >> 6, lane = threadIdx.x & 63;
        int w = b * 4 + wv;
        int n = cnt[w]; if (n > CAPI) n = CAPI;
        const int2* row = ed + (size_t)w * CAPI;
        float acc = 0.f;
        #pragma unroll 4
        for (int j = 0; j < n; ++j) {
            int2 e = row[j];
            acc += __int_as_float(e.y) * x[(size_t)e.x * D_ + lane];
        }
        y[(size_t)w * D_ + lane] = acc;
    } else {
        // edge MLP: 16 lanes/edge, 16 edges/block (4096 blocks)
        int w = (b - 5120) * 16 + (threadIdx.x >> 4);
        int q = threadIdx.x & 15;
        int r = sr[w], c = sc[w];
        float4 pa = ((const float4*)Pa)[c * 16 + q];
        float4 pb = ((const float4*)Pb)[r * 16 + q];
        float4 bb = ((const float4*)b1)[q];
        float4 ww = ((const float4*)w2)[q];
        float hx = fmaxf(pa.x + pb.x + bb.x, 0.f);
        float hy = fmaxf(pa.y + pb.y + bb.y, 0.f);
        float hz = fmaxf(pa.z + pb.z + bb.z, 0.f);
        float hw = fmaxf(pa.w + pb.w + bb.w, 0.f);
        float t = hx * ww.x + hy * ww.y + hz * ww.z + hw * ww.w;
        t += __shfl_xor(t, 8);
        t += __shfl_xor(t, 4);
        t += __shfl_xor(t, 2);
        t += __shfl_xor(t, 1);
        if (q == 0) {
            float p = t + b2[0];
            float ew = 1.f / (1.f + expf(-p));
            size_t base = (size_t)r * RCAPS;
            int hh = c & (RCAPS - 1);
            for (int probe = 0; probe < RCAPS; ++probe) {
                int prev = atomicCAS(&skey[base + hh], -1, c);
                if (prev == -1 || prev == c) { atomicAdd(&sval[base + hh], ew); break; }
                hh = (hh + 1) & (RCAPS - 1);
            }
        }
    }
}

// ---------------- L5: last LightGCN layer (user rows only) + user_e epilogue ----------------
__global__ __launch_bounds__(256) void spmm_last_kernel(const int* __restrict__ cnt, const int2* __restrict__ ed,
                                                        const float* __restrict__ ue,
                                                        const float* __restrict__ h1, const float* __restrict__ h2,
                                                        float* __restrict__ user_e) {
    int w = (blockIdx.x * 256 + threadIdx.x) >> 6;
    int lane = threadIdx.x & 63;
    int n = cnt[w]; if (n > CAPI) n = CAPI;
    const int2* row = ed + (size_t)w * CAPI;
    float acc = 0.f;
    #pragma unroll 4
    for (int j = 0; j < n; ++j) {
        int2 e = row[j];
        acc += __int_as_float(e.y) * h2[(size_t)e.x * D_ + lane];
    }
    size_t o = (size_t)w * D_ + lane;
    user_e[o] = 0.25f * (ue[o] + h1[o] + h2[o] + acc);
}

// ---------------- L6: social diffusion ----------------

__device__ __forceinline__ float wave_max_(float v) {
    #pragma unroll
    for (int o = 32; o > 0; o >>= 1) v = fmaxf(v, __shfl_xor(v, o));
    return v;
}
__device__ __forceinline__ float wave_sum_(float v) {
    #pragma unroll
    for (int o = 32; o > 0; o >>= 1) v += __shfl_xor(v, o);
    return v;
}

// block per user row. g2 loop is pure atomicAdd (no return dep) merged with ws1 gather;
// list built afterwards by ballot-compacted row2 scan fused with the max pass.
__global__ __launch_bounds__(256) void social_kernel(const int* __restrict__ skey,
                                                     const float* __restrict__ sval,
                                                     const float* __restrict__ user_e,
                                                     float* __restrict__ out) {
    __shared__ float row2[U_];        // 16 KB dense g2 scratch
    __shared__ int   list2[L2CAP];    // 4 KB
    __shared__ float val2[L2CAP];     // 4 KB
    __shared__ int   kcol_s[RCAPS];
    __shared__ float kval_s[RCAPS];
    __shared__ float wredm[4], wreds[4];
    __shared__ float accw[4][64];
    __shared__ int   cnt2_s, nnz_s;

    int i = blockIdx.x, t = threadIdx.x;
    int wv = t >> 6, lane = t & 63;

    {   // zero row2 with float4 stores
        float4* r4 = (float4*)row2;
        #pragma unroll
        for (int u = 0; u < 4; ++u) r4[t + 256 * u] = make_float4(0.f, 0.f, 0.f, 0.f);
    }
    if (t == 0) cnt2_s = 0;

    // wave 0: ballot-compact row i's hash
    if (wv == 0) {
        int k = skey[(size_t)i * RCAPS + lane];
        float v = sval[(size_t)i * RCAPS + lane];
        unsigned long long mask = __ballot(k >= 0);
        int pos = __popcll(mask & ((1ull << lane) - 1ull));
        if (k >= 0) { kcol_s[pos] = k; kval_s[pos] = v; }
        if (lane == 0) nnz_s = __popcll(mask);
    }
    __syncthreads();                                  // barrier 1
    int nnz = nnz_s;

    // per-wave redundant softmax1 (shfl only, zero barriers); nnz <= ~45 < 64
    float kv  = (lane < nnz) ? kval_s[lane] : -1e30f;
    float m1  = wave_max_(kv);
    float ex  = (lane < nnz) ? expf(kv - m1) : 0.f;
    float S1  = wave_sum_(ex);
    float inv1 = (nnz > 0) ? 1.f / S1 : 0.f;

    // g2 scatter + ws1 gather in one loop: 3 independent loads/iter, no atomic-return dep
    float acc = 0.f;
    for (int e = wv; e < nnz; e += 4) {
        int k = kcol_s[e];
        float vk = kval_s[e];
        int   c2 = skey[(size_t)k * RCAPS + lane];
        float v2 = sval[(size_t)k * RCAPS + lane];
        float ug = user_e[(size_t)k * D_ + lane];
        acc += (__shfl(ex, e) * inv1) * ug;
        if (c2 >= 0) atomicAdd(&row2[c2], vk * v2);
    }
    __syncthreads();                                  // barrier 2 (g2 complete)

    // scan row2: ballot-compact nonzeros into list2/val2 + local max (fused)
    float lm = -1e30f;
    int wbase = wv * 1024;
    #pragma unroll
    for (int u = 0; u < 16; ++u) {
        float v = row2[wbase + u * 64 + lane];
        lm = fmaxf(lm, v);                 // zeros can't win unless cnt2==0 (then unused)
        unsigned long long mask = __ballot(v > 0.f);
        if (mask) {                        // wave-uniform
            int cntw = __popcll(mask);
            int ofs = 0;
            if (lane == 0) ofs = atomicAdd(&cnt2_s, cntw);
            ofs = __shfl(ofs, 0);
            if (v > 0.f) {
                int idx = ofs + __popcll(mask & ((1ull << lane) - 1ull));
                if (idx < L2CAP) { list2[idx] = wbase + u * 64 + lane; val2[idx] = v; }
            }
        }
    }
    lm = wave_max_(lm);
    if (lane == 0) wredm[wv] = lm;
    __syncthreads();                                  // barrier 3 (cnt2 + list final)
    int cnt2 = cnt2_s;
    if (cnt2 > L2CAP) cnt2 = L2CAP;
    float m2 = fmaxf(fmaxf(wredm[0], wredm[1]), fmaxf(wredm[2], wredm[3]));
    float ls = 0.f;
    for (int e = t; e < cnt2; e += 256) {
        float exv = expf(val2[e] - m2);
        val2[e] = exv;
        ls += exv;
    }
    ls = wave_sum_(ls);
    if (lane == 0) wreds[wv] = ls;
    __syncthreads();                                  // barrier 4 (publishes val2)
    float S2 = wreds[0] + wreds[1] + wreds[2] + wreds[3];
    float inv2 = (cnt2 > 0) ? 1.f / S2 : 0.f;

    // weighted sum 2
    for (int e = wv; e < cnt2; e += 4) {
        acc += (val2[e] * inv2) * user_e[(size_t)list2[e] * D_ + lane];
    }
    accw[wv][lane] = acc;
    __syncthreads();                                  // barrier 5
    if (t < 64) {
        float s = accw[0][t] + accw[1][t] + accw[2][t] + accw[3][t];
        float ue = user_e[(size_t)i * D_ + t];
        out[i * D_ + t] = (4.f * ue + s) * (1.f / 3.f);
    }
}

// ---------------- Launch ----------------

extern "C" void kernel_launch(void* const* d_in, const int* in_sizes, int n_in,
                              void* d_out, int out_size, void* d_ws, size_t ws_size,
                              hipStream_t stream) {
    (void)in_sizes; (void)n_in; (void)out_size; (void)ws_size;
    const float* user_emb  = (const float*)d_in[0];
    const float* item_emb  = (const float*)d_in[1];
    const float* inter_vals= (const float*)d_in[2];
    const float* Wa        = (const float*)d_in[3];
    const float* Wb        = (const float*)d_in[4];
    const float* w1        = (const float*)d_in[5];
    const float* b1        = (const float*)d_in[6];
    const float* w2        = (const float*)d_in[7];
    const float* b2        = (const float*)d_in[8];
    const int* inter_rows  = (const int*)d_in[9];
    const int* inter_cols  = (const int*)d_in[10];
    const int* social_rows = (const int*)d_in[11];
    const int* social_cols = (const int*)d_in[12];
    float* out = (float*)d_out;

    char* w = (char*)d_ws;
    auto alloc = [&](size_t bytes) -> void* {
        void* p = (void*)w;
        w += (bytes + 255) & ~(size_t)255;
        return p;
    };
    float* h1     = (float*)alloc((size_t)N_ * D_ * 4);
    float* h2     = (float*)alloc((size_t)N_ * D_ * 4);
    float* user_e = (float*)alloc((size_t)U_ * D_ * 4);
    float* Pa     = (float*)alloc((size_t)U_ * D_ * 4);
    float* Pb     = (float*)alloc((size_t)U_ * D_ * 4);
    float* Wa2    = (float*)alloc(64 * 64 * 4);
    float* Wb2    = (float*)alloc(64 * 64 * 4);
    int*   cnt    = (int*)alloc((size_t)N_ * 4);
    int2*  ed     = (int2*)alloc((size_t)N_ * CAPI * 8);
    int*   skey   = (int*)alloc((size_t)U_ * RCAPS * 4);
    float* sval   = (float*)alloc((size_t)U_ * RCAPS * 4);

    // 6 dispatches; independent DAG branches packed into shared launches
    init_wab2_kernel<<<1056, 256, 0, stream>>>(cnt, skey, sval, Wa, Wb, w1, Wa2, Wb2);
    scatter_i_kernel<<<NEI / 256, 256, 0, stream>>>(inter_rows, inter_cols, inter_vals, cnt, ed);
    spmm1_pab_kernel<<<6144, 256, 0, stream>>>(cnt, ed, user_emb, item_emb, h1, Wa2, Wb2, Pa, Pb);
    spmm2_edge_kernel<<<9216, 256, 0, stream>>>(cnt, ed, h1, h2, social_rows, social_cols,
                                                Pa, Pb, b1, w2, b2, skey, sval);
    spmm_last_kernel<<<1024, 256, 0, stream>>>(cnt, ed, user_emb, h1, h2, user_e);
    social_kernel<<<U_, 256, 0, stream>>>(skey, sval, user_e, out);
}

// Round 7
// 226.226 us; speedup vs baseline: 1.0912x; 1.0912x over previous
//
#include <hip/hip_runtime.h>
#include <hip/hip_bf16.h>

#define U_    4096
#define I_    16384
#define D_    64
#define N_    20480     // U_ + I_
#define NEI   524288
#define NES   65536
#define CAPI  96        // interaction row-bucket capacity (mean 25.6; P(>=96) ~ 4e-25)
#define RCAPS 64        // social hash slots/row (mean nnz 16, max ~45)
#define SEG   384       // per-wave g2 first-touch segment (mean ~64/wave; 384 is >9 sigma)

// ---------------- L1: workspace init + weight fold (independent work fused) ----------------
__global__ __launch_bounds__(256) void init_wab2_kernel(int* __restrict__ cnt, int* __restrict__ skey,
                                                        float* __restrict__ sval,
                                                        const float* __restrict__ Wa,
                                                        const float* __restrict__ Wb,
                                                        const float* __restrict__ w1,
                                                        float* __restrict__ Wa2, float* __restrict__ Wb2) {
    int b = blockIdx.x;
    if (b < 1024) {
        int tid = b * 256 + threadIdx.x;
        int stride = 1024 * 256;
        for (int o = tid; o < N_; o += stride) cnt[o] = 0;
        for (int o = tid; o < U_ * RCAPS; o += stride) { skey[o] = -1; sval[o] = 0.f; }
    } else {
        // fold: Wa2 = Wa @ w1[0:64,:], Wb2 = Wb @ w1[64:128,:]  (32 blocks)
        int o = (b - 1024) * 256 + threadIdx.x;   // 8192
        int mat = o >> 12;
        int i = (o >> 6) & 63;
        int j = o & 63;
        const float* M  = mat ? Wb : Wa;
        const float* W1 = w1 + mat * 64 * 64;
        float s = 0.f;
        #pragma unroll 8
        for (int k = 0; k < 64; ++k) s += M[i * 64 + k] * W1[k * 64 + j];
        (mat ? Wb2 : Wa2)[i * 64 + j] = s;
    }
}

// ---------------- L2: bucketed interaction edge build ----------------
__global__ void scatter_i_kernel(const int* __restrict__ rows, const int* __restrict__ cols,
                                 const float* __restrict__ vals,
                                 int* __restrict__ cnt, int2* __restrict__ ed) {
    int e = blockIdx.x * 256 + threadIdx.x;
    int r = rows[e];
    int pos = atomicAdd(&cnt[r], 1);
    if (pos < CAPI) ed[(size_t)r * CAPI + pos] = make_int2(cols[e], __float_as_int(vals[e]));
}

// ---------------- L3: spmm layer 1 + Pa/Pb projection (independent; fused) ----------------
__global__ __launch_bounds__(256) void spmm1_pab_kernel(const int* __restrict__ cnt, const int2* __restrict__ ed,
                                                        const float* __restrict__ ue, const float* __restrict__ ie,
                                                        float* __restrict__ h1,
                                                        const float* __restrict__ Wa2, const float* __restrict__ Wb2,
                                                        float* __restrict__ Pa, float* __restrict__ Pb) {
    int b = blockIdx.x;
    int wv = threadIdx.x >> 6, lane = threadIdx.x & 63;
    if (b < 5120) {
        int w = b * 4 + wv;          // 20480 rows
        int n = cnt[w]; if (n > CAPI) n = CAPI;
        const int2* row = ed + (size_t)w * CAPI;
        float acc = 0.f;
        #pragma unroll 4
        for (int j = 0; j < n; ++j) {
            int2 e = row[j];
            int c = e.x; float v = __int_as_float(e.y);
            const float* xp = (c < U_) ? (ue + (size_t)c * D_) : (ie + (size_t)(c - U_) * D_);
            acc += v * xp[lane];
        }
        h1[(size_t)w * D_ + lane] = acc;
    } else {
        int w = (b - 5120) * 4 + wv; // 4096 user rows
        float x = ue[w * 64 + lane];
        float accA = 0.f, accB = 0.f;
        #pragma unroll 8
        for (int k = 0; k < 64; ++k) {
            float xk = __shfl(x, k);
            accA += xk * Wa2[k * 64 + lane];   // same addr across waves -> L2 broadcast
            accB += xk * Wb2[k * 64 + lane];
        }
        Pa[w * 64 + lane] = accA;
        Pb[w * 64 + lane] = accB;
    }
}

// ---------------- L4: spmm layer 2 + edge MLP/hash-insert (independent; fused) ----------------
__global__ __launch_bounds__(256) void spmm2_edge_kernel(const int* __restrict__ cnt, const int2* __restrict__ ed,
                                                         const float* __restrict__ x, float* __restrict__ y,
                                                         const int* __restrict__ sr, const int* __restrict__ sc,
                                                         const float* __restrict__ Pa, const float* __restrict__ Pb,
                                                         const float* __restrict__ b1, const float* __restrict__ w2,
                                                         const float* __restrict__ b2,
                                                         int* __restrict__ skey, float* __restrict__ sval) {
    int b = blockIdx.x;
    if (b < 5120) {
        int wv = threadIdx.x >> 6, lane = threadIdx.x & 63;
        int w = b * 4 + wv;
        int n = cnt[w]; if (n > CAPI) n = CAPI;
        const int2* row = ed + (size_t)w * CAPI;
        float acc = 0.f;
        #pragma unroll 4
        for (int j = 0; j < n; ++j) {
            int2 e = row[j];
            acc += __int_as_float(e.y) * x[(size_t)e.x * D_ + lane];
        }
        y[(size_t)w * D_ + lane] = acc;
    } else {
        // edge MLP: 16 lanes/edge, 16 edges/block (4096 blocks)
        int w = (b - 5120) * 16 + (threadIdx.x >> 4);
        int q = threadIdx.x & 15;
        int r = sr[w], c = sc[w];
        float4 pa = ((const float4*)Pa)[c * 16 + q];
        float4 pb = ((const float4*)Pb)[r * 16 + q];
        float4 bb = ((const float4*)b1)[q];
        float4 ww = ((const float4*)w2)[q];
        float hx = fmaxf(pa.x + pb.x + bb.x, 0.f);
        float hy = fmaxf(pa.y + pb.y + bb.y, 0.f);
        float hz = fmaxf(pa.z + pb.z + bb.z, 0.f);
        float hw = fmaxf(pa.w + pb.w + bb.w, 0.f);
        float t = hx * ww.x + hy * ww.y + hz * ww.z + hw * ww.w;
        t += __shfl_xor(t, 8);
        t += __shfl_xor(t, 4);
        t += __shfl_xor(t, 2);
        t += __shfl_xor(t, 1);
        if (q == 0) {
            float p = t + b2[0];
            float ew = 1.f / (1.f + expf(-p));
            size_t base = (size_t)r * RCAPS;
            int hh = c & (RCAPS - 1);
            for (int probe = 0; probe < RCAPS; ++probe) {
                int prev = atomicCAS(&skey[base + hh], -1, c);
                if (prev == -1 || prev == c) { atomicAdd(&sval[base + hh], ew); break; }
                hh = (hh + 1) & (RCAPS - 1);
            }
        }
    }
}

// ---------------- L5: last LightGCN layer (user rows only) + user_e epilogue ----------------
__global__ __launch_bounds__(256) void spmm_last_kernel(const int* __restrict__ cnt, const int2* __restrict__ ed,
                                                        const float* __restrict__ ue,
                                                        const float* __restrict__ h1, const float* __restrict__ h2,
                                                        float* __restrict__ user_e) {
    int w = (blockIdx.x * 256 + threadIdx.x) >> 6;
    int lane = threadIdx.x & 63;
    int n = cnt[w]; if (n > CAPI) n = CAPI;
    const int2* row = ed + (size_t)w * CAPI;
    float acc = 0.f;
    #pragma unroll 4
    for (int j = 0; j < n; ++j) {
        int2 e = row[j];
        acc += __int_as_float(e.y) * h2[(size_t)e.x * D_ + lane];
    }
    size_t o = (size_t)w * D_ + lane;
    user_e[o] = 0.25f * (ue[o] + h1[o] + h2[o] + acc);
}

// ---------------- L6: social diffusion ----------------

__device__ __forceinline__ float wave_max_(float v) {
    #pragma unroll
    for (int o = 32; o > 0; o >>= 1) v = fmaxf(v, __shfl_xor(v, o));
    return v;
}
__device__ __forceinline__ float wave_sum_(float v) {
    #pragma unroll
    for (int o = 32; o > 0; o >>= 1) v += __shfl_xor(v, o);
    return v;
}

// block per user row. Round-5 structure (first-touch list build during g2) with
// per-wave list segments: 4 independent LDS counters -> 1/4 the same-address
// atomic contention that single cnt2_s had.
__global__ __launch_bounds__(256) void social_kernel(const int* __restrict__ skey,
                                                     const float* __restrict__ sval,
                                                     const float* __restrict__ user_e,
                                                     float* __restrict__ out) {
    __shared__ float row2[U_];            // 16 KB dense g2 scratch
    __shared__ int   list2[4][SEG];       // 6 KB (per-wave segments)
    __shared__ float val2[4][SEG];        // 6 KB
    __shared__ int   kcol_s[RCAPS];
    __shared__ float kval_s[RCAPS];
    __shared__ float wredm[4], wreds[4];
    __shared__ float accw[4][64];
    __shared__ int   cntw[4];
    __shared__ int   nnz_s;

    int i = blockIdx.x, t = threadIdx.x;
    int wv = t >> 6, lane = t & 63;

    {   // zero row2 with float4 stores
        float4* r4 = (float4*)row2;
        #pragma unroll
        for (int u = 0; u < 4; ++u) r4[t + 256 * u] = make_float4(0.f, 0.f, 0.f, 0.f);
    }
    if (t < 4) cntw[t] = 0;

    // wave 0: ballot-compact row i's hash
    if (wv == 0) {
        int k = skey[(size_t)i * RCAPS + lane];
        float v = sval[(size_t)i * RCAPS + lane];
        unsigned long long mask = __ballot(k >= 0);
        int pos = __popcll(mask & ((1ull << lane) - 1ull));
        if (k >= 0) { kcol_s[pos] = k; kval_s[pos] = v; }
        if (lane == 0) nnz_s = __popcll(mask);
    }
    __syncthreads();                                  // barrier 1
    int nnz = nnz_s;

    // per-wave redundant softmax1 (shfl only, zero barriers); nnz <= ~45 < 64
    float kv  = (lane < nnz) ? kval_s[lane] : -1e30f;
    float m1  = wave_max_(kv);
    float ex  = (lane < nnz) ? expf(kv - m1) : 0.f;
    float S1  = wave_sum_(ex);
    float inv1 = (nnz > 0) ? 1.f / S1 : 0.f;

    // g2 = sum_k A[i,k] * A[k,:] via neighbor hash rows; first-touch appends to
    // this wave's own segment (exactly one toucher per col -> no duplicates).
    for (int e = wv; e < nnz; e += 4) {
        int k = kcol_s[e];
        float vk = kval_s[e];
        int   c2 = skey[(size_t)k * RCAPS + lane];
        float v2 = sval[(size_t)k * RCAPS + lane];
        if (c2 >= 0) {
            float old = atomicAdd(&row2[c2], vk * v2);
            if (old == 0.f) {
                int idx = atomicAdd(&cntw[wv], 1);
                if (idx < SEG) list2[wv][idx] = c2;
            }
        }
    }

    // weighted sum 1 (independent of row2)
    float acc = 0.f;
    for (int e = wv; e < nnz; e += 4) {
        float p = __shfl(ex, e) * inv1;
        acc += p * user_e[(size_t)kcol_s[e] * D_ + lane];
    }
    __syncthreads();                                  // barrier 2 (g2 + counters final)

    int len[4];
    #pragma unroll
    for (int s = 0; s < 4; ++s) { int L = cntw[s]; len[s] = (L > SEG) ? SEG : L; }
    int cnt2 = len[0] + len[1] + len[2] + len[3];

    // softmax2 max: all 256 threads stride each segment
    float lm = -1e30f;
    #pragma unroll
    for (int s = 0; s < 4; ++s)
        for (int e = t; e < len[s]; e += 256) lm = fmaxf(lm, row2[list2[s][e]]);
    lm = wave_max_(lm);
    if (lane == 0) wredm[wv] = lm;
    __syncthreads();                                  // barrier 3
    float m2 = fmaxf(fmaxf(wredm[0], wredm[1]), fmaxf(wredm[2], wredm[3]));
    float ls = 0.f;
    #pragma unroll
    for (int s = 0; s < 4; ++s)
        for (int e = t; e < len[s]; e += 256) {
            float exv = expf(row2[list2[s][e]] - m2);
            val2[s][e] = exv;
            ls += exv;
        }
    ls = wave_sum_(ls);
    if (lane == 0) wreds[wv] = ls;
    __syncthreads();                                  // barrier 4 (publishes val2)
    float S2 = wreds[0] + wreds[1] + wreds[2] + wreds[3];
    float inv2 = (cnt2 > 0) ? 1.f / S2 : 0.f;

    // weighted sum 2 (each wave strides every segment)
    #pragma unroll
    for (int s = 0; s < 4; ++s) {
        #pragma unroll 4
        for (int e = wv; e < len[s]; e += 4) {
            acc += (val2[s][e] * inv2) * user_e[(size_t)list2[s][e] * D_ + lane];
        }
    }
    accw[wv][lane] = acc;
    __syncthreads();                                  // barrier 5
    if (t < 64) {
        float s = accw[0][t] + accw[1][t] + accw[2][t] + accw[3][t];
        float ue = user_e[(size_t)i * D_ + t];
        out[i * D_ + t] = (4.f * ue + s) * (1.f / 3.f);
    }
}

// ---------------- Launch ----------------

extern "C" void kernel_launch(void* const* d_in, const int* in_sizes, int n_in,
                              void* d_out, int out_size, void* d_ws, size_t ws_size,
                              hipStream_t stream) {
    (void)in_sizes; (void)n_in; (void)out_size; (void)ws_size;
    const float* user_emb  = (const float*)d_in[0];
    const float* item_emb  = (const float*)d_in[1];
    const float* inter_vals= (const float*)d_in[2];
    const float* Wa        = (const float*)d_in[3];
    const float* Wb        = (const float*)d_in[4];
    const float* w1        = (const float*)d_in[5];
    const float* b1        = (const float*)d_in[6];
    const float* w2        = (const float*)d_in[7];
    const float* b2        = (const float*)d_in[8];
    const int* inter_rows  = (const int*)d_in[9];
    const int* inter_cols  = (const int*)d_in[10];
    const int* social_rows = (const int*)d_in[11];
    const int* social_cols = (const int*)d_in[12];
    float* out = (float*)d_out;

    char* w = (char*)d_ws;
    auto alloc = [&](size_t bytes) -> void* {
        void* p = (void*)w;
        w += (bytes + 255) & ~(size_t)255;
        return p;
    };
    float* h1     = (float*)alloc((size_t)N_ * D_ * 4);
    float* h2     = (float*)alloc((size_t)N_ * D_ * 4);
    float* user_e = (float*)alloc((size_t)U_ * D_ * 4);
    float* Pa     = (float*)alloc((size_t)U_ * D_ * 4);
    float* Pb     = (float*)alloc((size_t)U_ * D_ * 4);
    float* Wa2    = (float*)alloc(64 * 64 * 4);
    float* Wb2    = (float*)alloc(64 * 64 * 4);
    int*   cnt    = (int*)alloc((size_t)N_ * 4);
    int2*  ed     = (int2*)alloc((size_t)N_ * CAPI * 8);
    int*   skey   = (int*)alloc((size_t)U_ * RCAPS * 4);
    float* sval   = (float*)alloc((size_t)U_ * RCAPS * 4);

    // 6 dispatches; independent DAG branches packed into shared launches
    init_wab2_kernel<<<1056, 256, 0, stream>>>(cnt, skey, sval, Wa, Wb, w1, Wa2, Wb2);
    scatter_i_kernel<<<NEI / 256, 256, 0, stream>>>(inter_rows, inter_cols, inter_vals, cnt, ed);
    spmm1_pab_kernel<<<6144, 256, 0, stream>>>(cnt, ed, user_emb, item_emb, h1, Wa2, Wb2, Pa, Pb);
    spmm2_edge_kernel<<<9216, 256, 0, stream>>>(cnt, ed, h1, h2, social_rows, social_cols,
                                                Pa, Pb, b1, w2, b2, skey, sval);
    spmm_last_kernel<<<1024, 256, 0, stream>>>(cnt, ed, user_emb, h1, h2, user_e);
    social_kernel<<<U_, 256, 0, stream>>>(skey, sval, user_e, out);
}